// Round 1
// 1287.222 us; speedup vs baseline: 1.0210x; 1.0210x over previous
//
#include <hip/hip_runtime.h>
#include <hip/hip_bf16.h>

typedef long long ll;

// ---------------- fills ----------------
__global__ void fill_i_kernel(int* __restrict__ p, int v, ll n) {
    ll i = (ll)blockIdx.x * blockDim.x + threadIdx.x;
    if (i < n) p[i] = v;
}

// ---------------- hist+rank: rank[e] = cnt[col[e]]++  (ONE atomic per edge) ----------------
__global__ void hist_rank_kernel(const int* __restrict__ col, int* cnt,
                                 int* __restrict__ rank, ll E) {
    ll e = (ll)blockIdx.x * blockDim.x + threadIdx.x;
    if (e < E) rank[e] = atomicAdd(&cnt[col[e]], 1);
}

// ---------------- scan A: per-block sums of cnt ----------------
__global__ void scanA_kernel(const int* __restrict__ cnt, int* __restrict__ blockSums, int N) {
    __shared__ int s[256];
    int tid = threadIdx.x;
    int i = blockIdx.x * 256 + tid;
    s[tid] = (i < N) ? cnt[i] : 0;
    __syncthreads();
    for (int off = 128; off > 0; off >>= 1) {
        if (tid < off) s[tid] += s[tid + off];
        __syncthreads();
    }
    if (tid == 0) blockSums[blockIdx.x] = s[0];
}

// ---------------- scan B: exclusive scan of blockSums (single block, 512 thr) ----------------
__global__ void scanB_kernel(const int* __restrict__ blockSums, int* __restrict__ blockOff, int NB) {
    __shared__ int s[512];
    int tid = threadIdx.x;
    int v = (tid < NB) ? blockSums[tid] : 0;
    s[tid] = v;
    __syncthreads();
    for (int off = 1; off < 512; off <<= 1) {
        int t = (tid >= off) ? s[tid - off] : 0;
        __syncthreads();
        s[tid] += t;
        __syncthreads();
    }
    if (tid < NB) blockOff[tid] = s[tid] - v;  // exclusive
}

// ---------------- scan C: row_start = blockOff + excl-scan within block ----------------
__global__ void scanC_kernel(const int* __restrict__ cnt, const int* __restrict__ blockOff,
                             int* __restrict__ row_start, int N, int E) {
    __shared__ int s[256];
    int tid = threadIdx.x;
    int i = blockIdx.x * 256 + tid;
    int v = (i < N) ? cnt[i] : 0;
    s[tid] = v;
    __syncthreads();
    for (int off = 1; off < 256; off <<= 1) {
        int t = (tid >= off) ? s[tid - off] : 0;
        __syncthreads();
        s[tid] += t;
        __syncthreads();
    }
    if (i < N) row_start[i] = s[tid] - v + blockOff[blockIdx.x];
    if (i == N) row_start[N] = E;
}

// ---------------- placement (no atomics): csr_sw[row_st[col]+rank] = {src, bits(w)} ----------------
__global__ void place_kernel(const int* __restrict__ row, const int* __restrict__ col,
                             const float* __restrict__ ew, const int* __restrict__ rank,
                             const int* __restrict__ row_st, int2* __restrict__ csr_sw, ll E) {
    ll e = (ll)blockIdx.x * blockDim.x + threadIdx.x;
    if (e >= E) return;
    int c = col[e];
    int pos = row_st[c] + rank[e];
    csr_sw[pos] = make_int2(row[e], __float_as_int(ew[e]));
}

// ---------------- deg from CSR (no atomics): deg[n] = 1 + sum w ----------------
__global__ void deg_kernel(const int2* __restrict__ csr_sw, const int* __restrict__ row_st,
                           float* __restrict__ deg, int N) {
    int n = blockIdx.x * blockDim.x + threadIdx.x;
    if (n >= N) return;
    int p = row_st[n], pe = row_st[n + 1];
    float d = 1.0f;  // self-loop weight
    for (; p < pe; p++) d += __int_as_float(csr_sw[p].y);
    deg[n] = d;
}

// ---------------- dinv = 1/sqrt(deg) (in place) ----------------
__global__ void dinv_kernel(float* __restrict__ deg, int N) {
    int i = blockIdx.x * blockDim.x + threadIdx.x;
    if (i < N) {
        float d = deg[i];
        deg[i] = d > 0.0f ? 1.0f / sqrtf(d) : 0.0f;
    }
}

// ---------------- weight transpose: WT[k*192+j] = W[j*64+k], W is [192,64] ----------------
__global__ void wtrans_kernel(const float* __restrict__ Wih, const float* __restrict__ Whh,
                              float* __restrict__ WihT, float* __restrict__ WhhT) {
    int t = blockIdx.x * blockDim.x + threadIdx.x;  // 0..24575
    if (t >= 24576) return;
    int half = (t >= 12288) ? 1 : 0;
    int i = t - half * 12288;
    const float* src = half ? Whh : Wih;
    float* dst = half ? WhhT : WihT;
    int k = i / 192;
    int j = i - k * 192;
    dst[i] = src[j * 64 + k];
}

// ---------------- Wc[l] = Wg[l] @ WihT  (algebraic fusion of GGC per-layer GEMM into GRU gi) ----
// gi = (gather(ew, x) @ Wg) @ WihT = gather(ew, x) @ (Wg @ WihT)
__global__ void wcomb_kernel(const float* __restrict__ Wg, const float* __restrict__ WihT,
                             float* __restrict__ Wc) {
    int idx = blockIdx.x * 256 + threadIdx.x;  // 0..24575  ([2][64][192])
    if (idx >= 24576) return;
    int l = idx / 12288;
    int r = idx - l * 12288;
    int k = r / 192;
    int j = r - k * 192;
    const float* wg = Wg + l * 4096 + k * 64;  // Wg[l][k][t]
    float acc = 0.0f;
#pragma unroll 8
    for (int t = 0; t < 64; t++) acc += wg[t] * WihT[t * 192 + j];
    Wc[idx] = acc;
}

// ---------------- tiled GEMM: C[N,64] = A[N,K] @ B[K,64] (used for K=512 only now) ------------
template <int K>
__global__ __launch_bounds__(256) void gemm_tile(const float* __restrict__ A,
                                                 const float* __restrict__ B,
                                                 float* __restrict__ C, int N) {
    const int BM = 128, BK = 16;
    __shared__ float As[BK][132];   // +4 pad
    __shared__ float Bs[BK][64];
    int tid = threadIdx.x;
    int bm = blockIdx.x * BM;
    int tx = tid & 7;    // col group: cols tx*8..+7
    int ty = tid >> 3;   // 0..31: rows ty*4..+3
    int lr = tid >> 2;   // A loader: row 0..63 (two passes)
    int lc = tid & 3;    // A loader: k-chunk
    int br = tid >> 4;   // B loader: k row 0..15
    int bc = tid & 15;   // B loader: col chunk

    float acc[4][8];
#pragma unroll
    for (int i = 0; i < 4; i++)
#pragma unroll
        for (int j = 0; j < 8; j++) acc[i][j] = 0.0f;

    for (int k0 = 0; k0 < K; k0 += BK) {
#pragma unroll
        for (int rr = 0; rr < 2; rr++) {
            int r = lr + rr * 64;
            int gr = bm + r;
            gr = gr < N ? gr : N - 1;
            const float4 av = *(const float4*)&A[(ll)gr * K + k0 + lc * 4];
            As[lc * 4 + 0][r] = av.x;
            As[lc * 4 + 1][r] = av.y;
            As[lc * 4 + 2][r] = av.z;
            As[lc * 4 + 3][r] = av.w;
        }
        *(float4*)&Bs[br][bc * 4] = *(const float4*)&B[(ll)(k0 + br) * 64 + bc * 4];
        __syncthreads();
#pragma unroll
        for (int k = 0; k < BK; k++) {
            float4 a = *(const float4*)&As[k][ty * 4];
            float4 b0 = *(const float4*)&Bs[k][tx * 8];
            float4 b1 = *(const float4*)&Bs[k][tx * 8 + 4];
            float av[4] = {a.x, a.y, a.z, a.w};
            float bv[8] = {b0.x, b0.y, b0.z, b0.w, b1.x, b1.y, b1.z, b1.w};
#pragma unroll
            for (int i = 0; i < 4; i++)
#pragma unroll
                for (int j = 0; j < 8; j++) acc[i][j] += av[i] * bv[j];
        }
        __syncthreads();
    }
#pragma unroll
    for (int i = 0; i < 4; i++) {
        int gr = bm + ty * 4 + i;
        if (gr < N) {
            float4 v0 = make_float4(acc[i][0], acc[i][1], acc[i][2], acc[i][3]);
            float4 v1 = make_float4(acc[i][4], acc[i][5], acc[i][6], acc[i][7]);
            *(float4*)&C[(ll)gr * 64 + tx * 8] = v0;
            *(float4*)&C[(ll)gr * 64 + tx * 8 + 4] = v1;
        }
    }
}

// ---------------- gather64 + GCN1 epilogue, float4 lanes (16 lanes/node) ----------------
__global__ __launch_bounds__(256) void gather64_gcn1_kernel(
    const int2* __restrict__ csr_sw, const int* __restrict__ row_start,
    const float* __restrict__ h1, const float* __restrict__ dinv,
    const float* __restrict__ b1, float* __restrict__ xbuf, int N) {
    int t = blockIdx.x * 256 + threadIdx.x;
    int node = t >> 4;
    if (node >= N) return;
    int c0 = (t & 15) * 4;
    int p = row_start[node], pe = row_start[node + 1];
    float dn = dinv[node];
    float4 acc;
    {
        float4 h = *(const float4*)&h1[(ll)node * 64 + c0];
        float s = dn * dn;
        acc = make_float4(s * h.x, s * h.y, s * h.z, s * h.w);
    }
    for (; p + 4 <= pe; p += 4) {
        int2 s0 = csr_sw[p], s1 = csr_sw[p + 1], s2 = csr_sw[p + 2], s3 = csr_sw[p + 3];
        float w0 = dn * dinv[s0.x] * __int_as_float(s0.y);
        float w1 = dn * dinv[s1.x] * __int_as_float(s1.y);
        float w2 = dn * dinv[s2.x] * __int_as_float(s2.y);
        float w3 = dn * dinv[s3.x] * __int_as_float(s3.y);
        float4 r0 = *(const float4*)&h1[(ll)s0.x * 64 + c0];
        float4 r1 = *(const float4*)&h1[(ll)s1.x * 64 + c0];
        float4 r2 = *(const float4*)&h1[(ll)s2.x * 64 + c0];
        float4 r3 = *(const float4*)&h1[(ll)s3.x * 64 + c0];
        acc.x += w0 * r0.x + w1 * r1.x + w2 * r2.x + w3 * r3.x;
        acc.y += w0 * r0.y + w1 * r1.y + w2 * r2.y + w3 * r3.y;
        acc.z += w0 * r0.z + w1 * r1.z + w2 * r2.z + w3 * r3.z;
        acc.w += w0 * r0.w + w1 * r1.w + w2 * r2.w + w3 * r3.w;
    }
    for (; p < pe; p++) {
        int2 s = csr_sw[p];
        float w = dn * dinv[s.x] * __int_as_float(s.y);
        float4 r = *(const float4*)&h1[(ll)s.x * 64 + c0];
        acc.x += w * r.x; acc.y += w * r.y; acc.z += w * r.z; acc.w += w * r.w;
    }
    float4 b = *(const float4*)&b1[c0];
    float4 v = make_float4(acc.x + b.x, acc.y + b.y, acc.z + b.z, acc.w + b.w);
    v.x = v.x > 0.0f ? v.x : 0.0f;
    v.y = v.y > 0.0f ? v.y : 0.0f;
    v.z = v.z > 0.0f ? v.z : 0.0f;
    v.w = v.w > 0.0f ? v.w : 0.0f;
    *(float4*)&xbuf[(ll)node * 64 + c0] = v;
}

// ---------------- plain gather64 (GGC agg of raw x, raw weights), float4 lanes ----------------
__global__ __launch_bounds__(256) void gather64_kernel(
    const int2* __restrict__ csr_sw, const int* __restrict__ row_start,
    const float* __restrict__ src, float* __restrict__ dst, int N) {
    int t = blockIdx.x * 256 + threadIdx.x;
    int node = t >> 4;
    if (node >= N) return;
    int c0 = (t & 15) * 4;
    int p = row_start[node], pe = row_start[node + 1];
    float4 acc = make_float4(0.f, 0.f, 0.f, 0.f);
    for (; p + 4 <= pe; p += 4) {
        int2 s0 = csr_sw[p], s1 = csr_sw[p + 1], s2 = csr_sw[p + 2], s3 = csr_sw[p + 3];
        float w0 = __int_as_float(s0.y);
        float w1 = __int_as_float(s1.y);
        float w2 = __int_as_float(s2.y);
        float w3 = __int_as_float(s3.y);
        float4 r0 = *(const float4*)&src[(ll)s0.x * 64 + c0];
        float4 r1 = *(const float4*)&src[(ll)s1.x * 64 + c0];
        float4 r2 = *(const float4*)&src[(ll)s2.x * 64 + c0];
        float4 r3 = *(const float4*)&src[(ll)s3.x * 64 + c0];
        acc.x += w0 * r0.x + w1 * r1.x + w2 * r2.x + w3 * r3.x;
        acc.y += w0 * r0.y + w1 * r1.y + w2 * r2.y + w3 * r3.y;
        acc.z += w0 * r0.z + w1 * r1.z + w2 * r2.z + w3 * r3.z;
        acc.w += w0 * r0.w + w1 * r1.w + w2 * r2.w + w3 * r3.w;
    }
    for (; p < pe; p++) {
        int2 s = csr_sw[p];
        float w = __int_as_float(s.y);
        float4 r = *(const float4*)&src[(ll)s.x * 64 + c0];
        acc.x += w * r.x; acc.y += w * r.y; acc.z += w * r.z; acc.w += w * r.w;
    }
    *(float4*)&dst[(ll)node * 64 + c0] = acc;
}

// ---------------- fused GRU: gi = g@Wc (+bih), gh = x@WhhT (+bhh); T14 reg-prefetch ----------
__global__ __launch_bounds__(256) void gru_fused_kernel(
    float* __restrict__ x, const float* __restrict__ g,
    const float* __restrict__ WcT, const float* __restrict__ WhhT,
    const float* __restrict__ bih, const float* __restrict__ bhh, int N) {
    __shared__ float Aag[16][64];
    __shared__ float Axx[16][64];
    __shared__ float Bih[16][192];
    __shared__ float Bhh[16][192];
    float* BihF = &Bih[0][0];
    float* BhhF = &Bhh[0][0];

    int tid = threadIdx.x;
    int bm = blockIdx.x * 64;
    int rg = tid >> 5;
    int cg = tid & 31;
    int jb = cg * 2;
    int lm = tid >> 2;
    int lkc = tid & 3;
    int gr = bm + lm; gr = gr < N ? gr : N - 1;
    // B stage: flat 16B chunk f covers (k0+f/48)*192 + (f%48)*4 == k0*192 + f*4
    int f0 = tid, f1 = tid + 256, f2 = tid + 512;

    float air[2][8], aiz[2][8], ain[2][8], ahr[2][8], ahz[2][8], ahn[2][8];
#pragma unroll
    for (int j = 0; j < 2; j++)
#pragma unroll
        for (int i = 0; i < 8; i++) {
            air[j][i] = 0.f; aiz[j][i] = 0.f; ain[j][i] = 0.f;
            ahr[j][i] = 0.f; ahz[j][i] = 0.f; ahn[j][i] = 0.f;
        }

    // prefetch kb=0 into registers
    float4 pva = *(const float4*)&g[(ll)gr * 64 + lkc * 4];
    float4 pvx = *(const float4*)&x[(ll)gr * 64 + lkc * 4];
    float4 pbi0 = *(const float4*)&WcT[(ll)f0 * 4];
    float4 pbh0 = *(const float4*)&WhhT[(ll)f0 * 4];
    float4 pbi1 = *(const float4*)&WcT[(ll)f1 * 4];
    float4 pbh1 = *(const float4*)&WhhT[(ll)f1 * 4];
    float4 pbi2 = *(const float4*)&WcT[(ll)f2 * 4];
    float4 pbh2 = *(const float4*)&WhhT[(ll)f2 * 4];

    for (int kb = 0; kb < 4; kb++) {
        // commit prefetched tile to LDS
        Aag[lkc * 4 + 0][lm] = pva.x; Aag[lkc * 4 + 1][lm] = pva.y;
        Aag[lkc * 4 + 2][lm] = pva.z; Aag[lkc * 4 + 3][lm] = pva.w;
        Axx[lkc * 4 + 0][lm] = pvx.x; Axx[lkc * 4 + 1][lm] = pvx.y;
        Axx[lkc * 4 + 2][lm] = pvx.z; Axx[lkc * 4 + 3][lm] = pvx.w;
        *(float4*)&BihF[f0 * 4] = pbi0;
        *(float4*)&BhhF[f0 * 4] = pbh0;
        *(float4*)&BihF[f1 * 4] = pbi1;
        *(float4*)&BhhF[f1 * 4] = pbh1;
        *(float4*)&BihF[f2 * 4] = pbi2;
        *(float4*)&BhhF[f2 * 4] = pbh2;
        __syncthreads();
        if (kb < 3) {  // issue next-tile loads; latency hides under the 16-k compute below
            int k0 = (kb + 1) * 16;
            pva = *(const float4*)&g[(ll)gr * 64 + k0 + lkc * 4];
            pvx = *(const float4*)&x[(ll)gr * 64 + k0 + lkc * 4];
            pbi0 = *(const float4*)&WcT[(ll)k0 * 192 + f0 * 4];
            pbh0 = *(const float4*)&WhhT[(ll)k0 * 192 + f0 * 4];
            pbi1 = *(const float4*)&WcT[(ll)k0 * 192 + f1 * 4];
            pbh1 = *(const float4*)&WhhT[(ll)k0 * 192 + f1 * 4];
            pbi2 = *(const float4*)&WcT[(ll)k0 * 192 + f2 * 4];
            pbh2 = *(const float4*)&WhhT[(ll)k0 * 192 + f2 * 4];
        }
#pragma unroll
        for (int k = 0; k < 16; k++) {
            float4 g0 = *(const float4*)&Aag[k][rg * 8];
            float4 g1 = *(const float4*)&Aag[k][rg * 8 + 4];
            float4 x0 = *(const float4*)&Axx[k][rg * 8];
            float4 x1 = *(const float4*)&Axx[k][rg * 8 + 4];
            float2 wir = *(const float2*)&Bih[k][jb];
            float2 wiz = *(const float2*)&Bih[k][64 + jb];
            float2 win = *(const float2*)&Bih[k][128 + jb];
            float2 whr = *(const float2*)&Bhh[k][jb];
            float2 whz = *(const float2*)&Bhh[k][64 + jb];
            float2 whn = *(const float2*)&Bhh[k][128 + jb];
            float ag[8] = {g0.x, g0.y, g0.z, g0.w, g1.x, g1.y, g1.z, g1.w};
            float ax[8] = {x0.x, x0.y, x0.z, x0.w, x1.x, x1.y, x1.z, x1.w};
#pragma unroll
            for (int i = 0; i < 8; i++) {
                air[0][i] += ag[i] * wir.x; air[1][i] += ag[i] * wir.y;
                aiz[0][i] += ag[i] * wiz.x; aiz[1][i] += ag[i] * wiz.y;
                ain[0][i] += ag[i] * win.x; ain[1][i] += ag[i] * win.y;
                ahr[0][i] += ax[i] * whr.x; ahr[1][i] += ax[i] * whr.y;
                ahz[0][i] += ax[i] * whz.x; ahz[1][i] += ax[i] * whz.y;
                ahn[0][i] += ax[i] * whn.x; ahn[1][i] += ax[i] * whn.y;
            }
        }
        __syncthreads();
    }

    float bi_r0 = bih[jb], bi_r1 = bih[jb + 1];
    float bi_z0 = bih[64 + jb], bi_z1 = bih[64 + jb + 1];
    float bi_n0 = bih[128 + jb], bi_n1 = bih[128 + jb + 1];
    float bh_r0 = bhh[jb], bh_r1 = bhh[jb + 1];
    float bh_z0 = bhh[64 + jb], bh_z1 = bhh[64 + jb + 1];
    float bh_n0 = bhh[128 + jb], bh_n1 = bhh[128 + jb + 1];
#pragma unroll
    for (int i = 0; i < 8; i++) {
        int node = bm + rg * 8 + i;
        if (node >= N) break;
        float2 xo = *(const float2*)&x[(ll)node * 64 + jb];
        float r0 = 1.f / (1.f + expf(-(air[0][i] + bi_r0 + ahr[0][i] + bh_r0)));
        float z0 = 1.f / (1.f + expf(-(aiz[0][i] + bi_z0 + ahz[0][i] + bh_z0)));
        float n0 = tanhf(ain[0][i] + bi_n0 + r0 * (ahn[0][i] + bh_n0));
        float r1 = 1.f / (1.f + expf(-(air[1][i] + bi_r1 + ahr[1][i] + bh_r1)));
        float z1 = 1.f / (1.f + expf(-(aiz[1][i] + bi_z1 + ahz[1][i] + bh_z1)));
        float n1 = tanhf(ain[1][i] + bi_n1 + r1 * (ahn[1][i] + bh_n1));
        float2 xn;
        xn.x = (1.f - z0) * n0 + z0 * xo.x;
        xn.y = (1.f - z1) * n1 + z1 * xo.y;
        *(float2*)&x[(ll)node * 64 + jb] = xn;
    }
}

// ---------------- h2 = x @ W2 ([N,64]@[64,16]) — node per thread, W2 in LDS ----------------
__global__ __launch_bounds__(256) void gemm_w2_kernel(const float* __restrict__ x,
                                                      const float* __restrict__ W2,
                                                      float* __restrict__ h2, int N) {
    __shared__ float Ws[1024];
    int tid = threadIdx.x;
    *(float4*)&Ws[tid * 4] = *(const float4*)&W2[tid * 4];
    __syncthreads();
    int n = blockIdx.x * 256 + tid;
    if (n >= N) return;
    float acc[16];
#pragma unroll
    for (int c = 0; c < 16; c++) acc[c] = 0.0f;
    const float* xr = &x[(ll)n * 64];
#pragma unroll
    for (int kq = 0; kq < 16; kq++) {
        float4 xv = *(const float4*)&xr[kq * 4];
        float xs[4] = {xv.x, xv.y, xv.z, xv.w};
#pragma unroll
        for (int j = 0; j < 4; j++)
#pragma unroll
            for (int c = 0; c < 16; c++) acc[c] += xs[j] * Ws[(kq * 4 + j) * 16 + c];
    }
#pragma unroll
    for (int cq = 0; cq < 4; cq++)
        *(float4*)&h2[(ll)n * 16 + cq * 4] =
            make_float4(acc[cq * 4], acc[cq * 4 + 1], acc[cq * 4 + 2], acc[cq * 4 + 3]);
}

// ---------------- gather16 + self-loop + bias + log_softmax (norm on the fly) ----------------
__global__ __launch_bounds__(256) void gather16_final_kernel(
    const int2* __restrict__ csr_sw, const int* __restrict__ row_start,
    const float* __restrict__ h2, const float* __restrict__ dinv,
    const float* __restrict__ b2, float* __restrict__ out, int N) {
    int node = blockIdx.x * 16 + (threadIdx.x >> 4);
    if (node >= N) return;
    int lane = threadIdx.x & 15;
    int p = row_start[node], pe = row_start[node + 1];
    float dn = dinv[node];
    float acc = dn * dn * h2[(ll)node * 16 + lane];
    for (; p + 4 <= pe; p += 4) {
        int2 s0 = csr_sw[p], s1 = csr_sw[p + 1], s2 = csr_sw[p + 2], s3 = csr_sw[p + 3];
        float c0 = dn * dinv[s0.x] * __int_as_float(s0.y);
        float c1 = dn * dinv[s1.x] * __int_as_float(s1.y);
        float c2 = dn * dinv[s2.x] * __int_as_float(s2.y);
        float c3 = dn * dinv[s3.x] * __int_as_float(s3.y);
        acc += c0 * h2[(ll)s0.x * 16 + lane];
        acc += c1 * h2[(ll)s1.x * 16 + lane];
        acc += c2 * h2[(ll)s2.x * 16 + lane];
        acc += c3 * h2[(ll)s3.x * 16 + lane];
    }
    for (; p < pe; p++) {
        int2 s = csr_sw[p];
        acc += dn * dinv[s.x] * __int_as_float(s.y) * h2[(ll)s.x * 16 + lane];
    }
    float v = acc + b2[lane];
    float mx = v;
    for (int m = 1; m < 16; m <<= 1) mx = fmaxf(mx, __shfl_xor(mx, m, 16));
    float ex = expf(v - mx);
    float sum = ex;
    for (int m = 1; m < 16; m <<= 1) sum += __shfl_xor(sum, m, 16);
    out[(ll)node * 16 + lane] = v - mx - logf(sum);
}

extern "C" void kernel_launch(void* const* d_in, const int* in_sizes, int n_in,
                              void* d_out, int out_size, void* d_ws, size_t ws_size,
                              hipStream_t stream) {
    const float* x   = (const float*)d_in[0];
    const int*   ei  = (const int*)d_in[1];
    const float* ew  = (const float*)d_in[2];
    const float* W1  = (const float*)d_in[3];
    const float* b1  = (const float*)d_in[4];
    const float* Wg  = (const float*)d_in[5];
    const float* Wih = (const float*)d_in[6];
    const float* Whh = (const float*)d_in[7];
    const float* bih = (const float*)d_in[8];
    const float* bhh = (const float*)d_in[9];
    const float* W2  = (const float*)d_in[10];
    const float* b2  = (const float*)d_in[11];

    const int N = in_sizes[0] / 512;   // 100000
    const ll  E = in_sizes[2];         // 3200000
    const int* row = ei;
    const int* col = ei + E;

    // ---- workspace carve ----
    char* base = (char*)d_ws;
    size_t off = 0;
    auto carveF = [&](ll n) { float* p = (float*)(base + off); off += (size_t)n * 4; return p; };
    auto carveI = [&](ll n) { int*   p = (int*)(base + off);   off += (size_t)n * 4; return p; };
    float* dinv    = carveF(N);
    float* bufA    = carveF((ll)N * 64);
    float* bufB    = carveF((ll)N * 64);
    float* xbuf    = carveF((ll)N * 64);
    int*   rank    = carveI(E);
    int2*  csr_sw  = (int2*)(base + off); off += (size_t)E * 8;
    int*   row_st  = carveI(N + 1);
    int*   cnt     = carveI(N);
    int*   blkSums = carveI(512);
    int*   blkOff  = carveI(512);
    float* WihT    = carveF(12288);
    float* WhhT    = carveF(12288);
    float* Wc      = carveF(24576);   // [2][64][192]
    (void)ws_size;

    const int B = 256;
    const int NB = (N + 255) / 256;

    // ---- CSR build (1 atomic/edge) + deg/dinv from CSR ----
    fill_i_kernel<<<(N + B - 1) / B, B, 0, stream>>>(cnt, 0, N);
    hist_rank_kernel<<<(int)((E + B - 1) / B), B, 0, stream>>>(col, cnt, rank, E);
    scanA_kernel<<<NB, 256, 0, stream>>>(cnt, blkSums, N);
    scanB_kernel<<<1, 512, 0, stream>>>(blkSums, blkOff, NB);
    scanC_kernel<<<NB, 256, 0, stream>>>(cnt, blkOff, row_st, N, (int)E);
    place_kernel<<<(int)((E + B - 1) / B), B, 0, stream>>>(row, col, ew, rank, row_st, csr_sw, E);
    deg_kernel<<<(N + B - 1) / B, B, 0, stream>>>(csr_sw, row_st, dinv, N);
    dinv_kernel<<<(N + B - 1) / B, B, 0, stream>>>(dinv, N);
    wtrans_kernel<<<(24576 + B - 1) / B, B, 0, stream>>>(Wih, Whh, WihT, WhhT);
    wcomb_kernel<<<96, 256, 0, stream>>>(Wg, WihT, Wc);

    // ---- GCN conv 1 ----
    gemm_tile<512><<<(N + 127) / 128, 256, 0, stream>>>(x, W1, bufA, N);
    gather64_gcn1_kernel<<<(N * 16 + 255) / 256, 256, 0, stream>>>(csr_sw, row_st, bufA, dinv,
                                                                   b1, xbuf, N);

    // ---- 2x GatedGraphConv (GEMM folded into GRU via Wc = Wg @ WihT) ----
    for (int l = 0; l < 2; l++) {
        gather64_kernel<<<(N * 16 + 255) / 256, 256, 0, stream>>>(csr_sw, row_st, xbuf, bufB, N);
        gru_fused_kernel<<<(N + 63) / 64, 256, 0, stream>>>(xbuf, bufB, Wc + (ll)l * 12288,
                                                            WhhT, bih, bhh, N);
    }

    // ---- GCN conv 2 + log_softmax ----
    gemm_w2_kernel<<<(N + 255) / 256, 256, 0, stream>>>(xbuf, W2, bufA, N);
    gather16_final_kernel<<<(N + 15) / 16, 256, 0, stream>>>(csr_sw, row_st, bufA, dinv, b2,
                                                             (float*)d_out, N);
}